// Round 5
// baseline (189.353 us; speedup 1.0000x reference)
//
#include <hip/hip_runtime.h>
#include <hip/hip_bf16.h>
#include <math.h>

#define BB 4
#define SS 512
#define HH 8
#define DD 64
#define RR 64
#define OO 512

typedef _Float16 f16;
typedef __attribute__((ext_vector_type(8))) _Float16 f16x8;
typedef __attribute__((ext_vector_type(4))) _Float16 f16x4;
typedef __attribute__((ext_vector_type(4))) float f32x4;

// ws byte offsets
#define WS_QHS   0u            // 2MB f16 q, pre-swizzled LDS tile images [z][qb][2048B]
#define WS_KHS   (2u<<20)      // 2MB f16 k panels [z][p][8192B] swz128
#define WS_VTS   (4u<<20)      // 2MB f16 v^T panels [z][p][8192B] swz128
#define WS_CTXH  (6u<<20)      // 2MB f16 ctx [b,s,h*d] linear
#define WS_ADJ8  (8u<<20)      // 1MB u8 packed adj|mask<<7
#define WS_WT    (12u<<20)     // 4 x 512KB f16 transposed weights
#define WS_EVT   (14u<<20)     // 8KB f16 emb_v^T

// XOR swizzle (T2/G4): spread same-16B-column rows across 8 bank slots
__device__ __forceinline__ int swz128(int row, int b)  { return row*128  + (b ^ ((row&7)<<4)); }
__device__ __forceinline__ int swz1024(int row, int b) { return row*1024 + (b ^ ((row&7)<<4)); }

__device__ __forceinline__ void pack8(const float4& x, const float4& y, f16x8& o) {
    o[0]=(f16)x.x; o[1]=(f16)x.y; o[2]=(f16)x.z; o[3]=(f16)x.w;
    o[4]=(f16)y.x; o[5]=(f16)y.y; o[6]=(f16)y.z; o[7]=(f16)y.w;
}

// ---------------------------------------------------------------------------
// Merged: blocks <1024 pack adj+mask -> u8 (with per-block dtype detection);
// blocks >=1024 transpose weights to f16 WT and emb_v -> evt.
// ---------------------------------------------------------------------------
__global__ __launch_bounds__(256) void k_prep_all(
    const int* __restrict__ adj, const void* __restrict__ mask,
    const float* __restrict__ Wq, const float* __restrict__ Wk,
    const float* __restrict__ Wv, const float* __restrict__ Wo,
    const float* __restrict__ emb_v,
    unsigned char* __restrict__ adj8, f16* __restrict__ WT, f16* __restrict__ evt)
{
    const int tid = threadIdx.x;
    const int bid = blockIdx.x;
    __shared__ int s_odd, s_big;
    __shared__ float tile[64][65];

    if (bid < 1024) {
        if (tid == 0) { s_odd = 0; s_big = 0; }
        __syncthreads();
        int odd = 0, big = 0;
        const unsigned int* mu = (const unsigned int*)mask;
        for (int i = tid; i < 512; i += 256) {
            odd |= (adj[2*i + 1] != 0);
            big |= (mu[i] > 1u);
        }
        if (odd) atomicOr(&s_odd, 1);
        if (big) atomicOr(&s_big, 1);
        __syncthreads();
        const int f64 = s_odd ? 0 : 1;
        const int fbyte = s_big;

        const int t = bid * 256 + tid;           // u32 output index
        const int e0 = t * 4;
        const int b = e0 >> 18, k0 = e0 & 511;
        int a[4];
        if (f64) {
            const int4 A = ((const int4*)adj)[2*t];
            const int4 Bv = ((const int4*)adj)[2*t + 1];
            a[0] = A.x; a[1] = A.z; a[2] = Bv.x; a[3] = Bv.z;
        } else {
            const int4 A = ((const int4*)adj)[t];
            a[0] = A.x; a[1] = A.y; a[2] = A.z; a[3] = A.w;
        }
        unsigned int mbits;
        if (fbyte) {
            const unsigned int mw = *(const unsigned int*)((const unsigned char*)mask + b*512 + k0);
            mbits = ((mw & 255u) ? 1u : 0) | (((mw >> 8) & 255u) ? 2u : 0)
                  | (((mw >> 16) & 255u) ? 4u : 0) | (((mw >> 24) & 255u) ? 8u : 0);
        } else {
            const int4 mv = ((const int4*)mask)[(b*512 + k0) >> 2];
            mbits = (mv.x ? 1u : 0) | (mv.y ? 2u : 0) | (mv.z ? 4u : 0) | (mv.w ? 8u : 0);
        }
        unsigned int w = 0;
#pragma unroll
        for (int j = 0; j < 4; ++j)
            w |= ((unsigned)(a[j] & 63) | (((mbits >> j) & 1u) << 7)) << (8*j);
        ((unsigned int*)adj8)[t] = w;
        return;
    }

    const int pid = bid - 1024;                  // [0, 320)
    const int z = pid >> 6, rem = pid & 63;
    const int r = tid >> 2, c4 = (tid & 3) * 16;
    if (z < 4) {
        const float* W = (z==0)?Wq:(z==1)?Wk:(z==2)?Wv:Wo;
        f16* T = WT + (size_t)z * 262144;
        const int n0 = (rem & 7) * 64, k0 = (rem >> 3) * 64;
#pragma unroll
        for (int u = 0; u < 4; ++u) {
            const float4 w4 = *(const float4*)&W[(size_t)(k0 + r)*512 + n0 + c4 + u*4];
            tile[r][c4+u*4+0] = w4.x; tile[r][c4+u*4+1] = w4.y;
            tile[r][c4+u*4+2] = w4.z; tile[r][c4+u*4+3] = w4.w;
        }
        __syncthreads();
        f16x8 v0, v1;
#pragma unroll
        for (int j = 0; j < 8; ++j) { v0[j] = (f16)tile[c4+j][r]; v1[j] = (f16)tile[c4+8+j][r]; }
        f16* dst = &T[(size_t)(n0 + r)*512 + k0 + c4];
        *(f16x8*)dst = v0; *(f16x8*)(dst + 8) = v1;
    } else {
        if (rem) return;
#pragma unroll
        for (int u = 0; u < 4; ++u) {
            const float4 w4 = *(const float4*)&emb_v[(size_t)r*64 + c4 + u*4];
            tile[r][c4+u*4+0] = w4.x; tile[r][c4+u*4+1] = w4.y;
            tile[r][c4+u*4+2] = w4.z; tile[r][c4+u*4+3] = w4.w;
        }
        __syncthreads();
        f16x8 v0, v1;
#pragma unroll
        for (int j = 0; j < 8; ++j) { v0[j] = (f16)tile[c4+j][r]; v1[j] = (f16)tile[c4+8+j][r]; }
        f16* dst = &evt[(size_t)r*64 + c4];
        *(f16x8*)dst = v0; *(f16x8*)(dst + 8) = v1;
    }
}

// ---------------------------------------------------------------------------
// QKV projection, f16 MFMA, double-buffered. Outputs are PRE-SWIZZLED LDS
// tile images: qhs [z][qb][16x64 swz128], khs [z][p][64x64 swz128],
// vts [z][p][64(d)x64(s) swz128] so k_attn staging is a linear byte copy.
// ---------------------------------------------------------------------------
__global__ __launch_bounds__(256) void k_proj(
    const float* __restrict__ query, const float* __restrict__ key, const float* __restrict__ value,
    const f16* __restrict__ WT,
    const float* __restrict__ bq, const float* __restrict__ bk, const float* __restrict__ bv,
    char* __restrict__ qhs, char* __restrict__ khs, char* __restrict__ vts)
{
    const int z = blockIdx.z;
    const float* A    = (z == 0) ? query : (z == 1) ? key : value;
    const f16*   Bt   = WT + (size_t)z * 262144;
    const float* bias = (z == 0) ? bq : (z == 1) ? bk : bv;

    const int n0 = blockIdx.x * 64;
    const int m0 = blockIdx.y * 64;
    __shared__ char Ab[2][8192];
    __shared__ char Bb[2][8192];
    const int tid = threadIdx.x;
    const int wid = tid >> 6, l = tid & 63;
    const int wr = wid >> 1, wc = wid & 1;
    const int lr = l & 15, lg = l >> 4;
    const int sr = tid >> 2, sc = (tid & 3) * 16;

    const float* Ap = &A[(size_t)(m0 + sr)*512 + sc];
    const f16*   Bp = &Bt[(size_t)(n0 + sr)*512 + sc];

    f32x4 acc[2][2];
#pragma unroll
    for (int mi = 0; mi < 2; ++mi)
#pragma unroll
        for (int ni = 0; ni < 2; ++ni) acc[mi][ni] = (f32x4){0.f,0.f,0.f,0.f};

    float4 a4[4]; f16x8 b0, b1;
#pragma unroll
    for (int u = 0; u < 4; ++u) a4[u] = *(const float4*)(Ap + u*4);
    b0 = *(const f16x8*)Bp; b1 = *(const f16x8*)(Bp + 8);
    {
        f16x8 p0, p1;
        pack8(a4[0], a4[1], p0); pack8(a4[2], a4[3], p1);
        *(f16x8*)(Ab[0] + swz128(sr, sc*2))    = p0;
        *(f16x8*)(Ab[0] + swz128(sr, sc*2+16)) = p1;
        *(f16x8*)(Bb[0] + swz128(sr, sc*2))    = b0;
        *(f16x8*)(Bb[0] + swz128(sr, sc*2+16)) = b1;
    }
#pragma unroll
    for (int t = 0; t < 8; ++t) {
        __syncthreads();
        if (t < 7) {
#pragma unroll
            for (int u = 0; u < 4; ++u) a4[u] = *(const float4*)(Ap + (t+1)*64 + u*4);
            b0 = *(const f16x8*)(Bp + (t+1)*64);
            b1 = *(const f16x8*)(Bp + (t+1)*64 + 8);
        }
        const char* Ac = Ab[t & 1];
        const char* Bc = Bb[t & 1];
        f16x8 fa[2][2], fb[2][2];
#pragma unroll
        for (int mi = 0; mi < 2; ++mi) {
            const int row = wr*32 + mi*16 + lr;
#pragma unroll
            for (int ks = 0; ks < 2; ++ks)
                fa[mi][ks] = *(const f16x8*)(Ac + swz128(row, ks*64 + lg*16));
        }
#pragma unroll
        for (int ni = 0; ni < 2; ++ni) {
            const int row = wc*32 + ni*16 + lr;
#pragma unroll
            for (int ks = 0; ks < 2; ++ks)
                fb[ni][ks] = *(const f16x8*)(Bc + swz128(row, ks*64 + lg*16));
        }
#pragma unroll
        for (int ks = 0; ks < 2; ++ks)
#pragma unroll
            for (int mi = 0; mi < 2; ++mi)
#pragma unroll
                for (int ni = 0; ni < 2; ++ni)
                    acc[mi][ni] = __builtin_amdgcn_mfma_f32_16x16x32_f16(
                        fa[mi][ks], fb[ni][ks], acc[mi][ni], 0, 0, 0);
        if (t < 7) {
            f16x8 p0, p1;
            pack8(a4[0], a4[1], p0); pack8(a4[2], a4[3], p1);
            char* An = Ab[(t+1) & 1];
            char* Bn = Bb[(t+1) & 1];
            *(f16x8*)(An + swz128(sr, sc*2))    = p0;
            *(f16x8*)(An + swz128(sr, sc*2+16)) = p1;
            *(f16x8*)(Bn + swz128(sr, sc*2))    = b0;
            *(f16x8*)(Bn + swz128(sr, sc*2+16)) = b1;
        }
    }

#pragma unroll
    for (int ni = 0; ni < 2; ++ni) {
        const int n = n0 + wc*32 + ni*16 + lr;
        const float bv_ = bias[n];
        const int h = n >> 6, d = n & 63;
#pragma unroll
        for (int mi = 0; mi < 2; ++mi)
#pragma unroll
            for (int e = 0; e < 4; ++e) {
                const int m = m0 + wr*32 + mi*16 + lg*4 + e;
                const int b = m >> 9, s = m & 511;
                const int zq = b*HH + h;
                const f16 v = (f16)(acc[mi][ni][e] + bv_);
                if (z == 0)
                    *(f16*)(qhs + ((size_t)(zq*32 + (s>>4)))*2048 + swz128(s & 15, d*2)) = v;
                else if (z == 1)
                    *(f16*)(khs + ((size_t)(zq*8 + (s>>6)))*8192 + swz128(s & 63, d*2)) = v;
                else
                    *(f16*)(vts + ((size_t)(zq*8 + (s>>6)))*8192 + swz128(d, (s & 63)*2)) = v;
            }
    }
}

// ---------------------------------------------------------------------------
// Fused attention. 4 waves, 16 q-rows x one (b,h). Scores spill to LDS f16
// per panel (no 32-reg live accumulator). Softmax = readback pass with global
// max; buckets accumulated unnormalized; 1/T folded into attn-write pass and
// PV epilogue. All staging is a linear copy of pre-swizzled global images.
// ---------------------------------------------------------------------------
__global__ __launch_bounds__(256, 4) void k_attn(
    const char* __restrict__ qhs, const char* __restrict__ khs, const char* __restrict__ vts,
    const unsigned char* __restrict__ adj8, const float* __restrict__ emb_k,
    const f16* __restrict__ evt, float* __restrict__ attn, f16* __restrict__ ctxh)
{
    // bijective XCD swizzle: 1024 blocks -> 128 consecutive per XCD
    const int wg = (blockIdx.x & 7) * 128 + (blockIdx.x >> 3);
    const int z = wg >> 5, qb = wg & 31;
    const int b = z >> 3, h = z & 7;
    const int q0 = qb * 16;
    const int tid = threadIdx.x, w = tid >> 6, l = tid & 63;
    const int lr = l & 15, lg = l >> 4;

    __shared__ char KV[2][8192];     // K/V panel, pre-swizzled image
    __shared__ char Qb_[2048];       // Q tile, pre-swizzled image
    __shared__ char PS[16384];       // scores/P~ f16 [16][512], swz1024
    __shared__ float QW[16][65];     // qe table, then bucket accumulator
    __shared__ float red_m[4][16], red_s[4][16];
    __shared__ float invT_s[16];

    const char* khz = khs + (size_t)z * 65536;
    const char* vtz = vts + (size_t)z * 65536;

    // ---- P0: issue independent loads; stage Q ----
    unsigned int avw[8];
    const unsigned char* arow = &adj8[((size_t)b*SS + q0 + lr)*SS];
#pragma unroll
    for (int p = 0; p < 8; ++p)
        avw[p] = *(const unsigned int*)(arow + p*64 + w*16 + lg*4);
    f32x4 e4[4];
    {
        const float* ep = &emb_k[(size_t)(w*16 + lr)*DD];
        e4[0] = *(const f32x4*)(ep + lg*8);
        e4[1] = *(const f32x4*)(ep + lg*8 + 4);
        e4[2] = *(const f32x4*)(ep + 32 + lg*8);
        e4[3] = *(const f32x4*)(ep + 32 + lg*8 + 4);
    }
    f16x8 st0 = *(const f16x8*)(khz + tid*16);
    f16x8 st1 = *(const f16x8*)(khz + 4096 + tid*16);
    {
        const char* qhz = qhs + ((size_t)z*32 + qb) * 2048;
        *(f16x4*)(Qb_ + tid*8) = *(const f16x4*)(qhz + tid*8);
    }
    __syncthreads();

    // ---- P1: qe via MFMA; stage K panel 0 ----
    const f16x8 fb0 = *(const f16x8*)(Qb_ + swz128(lr, lg*16));
    const f16x8 fb1 = *(const f16x8*)(Qb_ + swz128(lr, 64 + lg*16));
    {
        f16x8 fe0, fe1;
#pragma unroll
        for (int j = 0; j < 4; ++j) {
            fe0[j] = (f16)e4[0][j]; fe0[4+j] = (f16)e4[1][j];
            fe1[j] = (f16)e4[2][j]; fe1[4+j] = (f16)e4[3][j];
        }
        f32x4 aq = (f32x4){0.f,0.f,0.f,0.f};
        aq = __builtin_amdgcn_mfma_f32_16x16x32_f16(fe0, fb0, aq, 0, 0, 0);
        aq = __builtin_amdgcn_mfma_f32_16x16x32_f16(fe1, fb1, aq, 0, 0, 0);
#pragma unroll
        for (int e = 0; e < 4; ++e) QW[lr][w*16 + lg*4 + e] = aq[e];
    }
    *(f16x8*)(KV[0] + tid*16)        = st0;
    *(f16x8*)(KV[0] + 4096 + tid*16) = st1;
    __syncthreads();

    // ---- P2: QK^T 8 panels, scores -> PS (f16), running max in reg ----
    float mx = -1e30f;
#pragma unroll
    for (int p = 0; p < 8; ++p) {
        if (p < 7) {
            st0 = *(const f16x8*)(khz + (p+1)*8192 + tid*16);
            st1 = *(const f16x8*)(khz + (p+1)*8192 + 4096 + tid*16);
        }
        const char* Kc = KV[p & 1];
        const f16x8 fa0 = *(const f16x8*)(Kc + swz128(w*16 + lr, lg*16));
        const f16x8 fa1 = *(const f16x8*)(Kc + swz128(w*16 + lr, 64 + lg*16));
        f32x4 a = (f32x4){0.f,0.f,0.f,0.f};
        a = __builtin_amdgcn_mfma_f32_16x16x32_f16(fa0, fb0, a, 0, 0, 0);
        a = __builtin_amdgcn_mfma_f32_16x16x32_f16(fa1, fb1, a, 0, 0, 0);
        const unsigned av = avw[p];
        f16x4 sv;
#pragma unroll
        for (int e = 0; e < 4; ++e) {
            const unsigned ab = (av >> (8*e)) & 255u;
            float s = (a[e] + QW[lr][ab & 63]) * 0.125f;
            s = (ab & 128u) ? -1e30f : s;
            mx = fmaxf(mx, s);
            sv[e] = (f16)s;
        }
        *(f16x4*)(PS + swz1024(lr, p*128 + w*32 + lg*8)) = sv;
        if (p < 7) {
            char* Kn = KV[(p+1) & 1];
            *(f16x8*)(Kn + tid*16)        = st0;
            *(f16x8*)(Kn + 4096 + tid*16) = st1;
            __syncthreads();
        }
    }

    // ---- P3: global row max; zero buckets; stage V0 loads ----
    mx = fmaxf(mx, __shfl_xor(mx, 16, 64));
    mx = fmaxf(mx, __shfl_xor(mx, 32, 64));
    if (l < 16) red_m[w][lr] = mx;
    __syncthreads();                              // B1: red_m ready, qe reads done
    f16x8 v0 = *(const f16x8*)(vtz + tid*16);
    f16x8 v1 = *(const f16x8*)(vtz + 4096 + tid*16);
    for (int i = tid; i < 16*65; i += 256) (&QW[0][0])[i] = 0.f;
    const float M = fmaxf(fmaxf(red_m[0][lr], red_m[1][lr]),
                          fmaxf(red_m[2][lr], red_m[3][lr]));
    __syncthreads();                              // B2: buckets zeroed

    // ---- pass A: exp + sum + bucket atomics + writeback; stage V0 ----
    float sm = 0.f;
#pragma unroll
    for (int p = 0; p < 8; ++p) {
        f16x4* ps = (f16x4*)(PS + swz1024(lr, p*128 + w*32 + lg*8));
        const f16x4 sv = *ps;
        const float e0 = __expf((float)sv[0] - M);
        const float e1 = __expf((float)sv[1] - M);
        const float e2 = __expf((float)sv[2] - M);
        const float e3 = __expf((float)sv[3] - M);
        sm += (e0 + e1) + (e2 + e3);
        f16x4 ev; ev[0]=(f16)e0; ev[1]=(f16)e1; ev[2]=(f16)e2; ev[3]=(f16)e3;
        *ps = ev;
        const unsigned av = avw[p];
        atomicAdd(&QW[lr][(av      ) & 63], e0);
        atomicAdd(&QW[lr][(av >>  8) & 63], e1);
        atomicAdd(&QW[lr][(av >> 16) & 63], e2);
        atomicAdd(&QW[lr][(av >> 24) & 63], e3);
    }
    sm += __shfl_xor(sm, 16, 64);
    sm += __shfl_xor(sm, 32, 64);
    if (l < 16) red_s[w][lr] = sm;
    *(f16x8*)(KV[0] + tid*16)        = v0;
    *(f16x8*)(KV[0] + 4096 + tid*16) = v1;
    __syncthreads();                              // B3: PS=P~, buckets, V0, red_s
    if (tid < 16)
        invT_s[tid] = 1.f / (red_s[0][tid] + red_s[1][tid] + red_s[2][tid] + red_s[3][tid]);

    // ---- P4: PV, 8 panels double-buffered ----
    f32x4 acc2 = (f32x4){0.f,0.f,0.f,0.f};
#pragma unroll
    for (int p = 0; p < 8; ++p) {
        if (p < 7) {
            v0 = *(const f16x8*)(vtz + (p+1)*8192 + tid*16);
            v1 = *(const f16x8*)(vtz + (p+1)*8192 + 4096 + tid*16);
        }
        const char* Vc = KV[p & 1];
#pragma unroll
        for (int ks = 0; ks < 2; ++ks) {
            const f16x8 fa = *(const f16x8*)(PS + swz1024(lr, p*128 + ks*64 + lg*16));
            const f16x8 fb = *(const f16x8*)(Vc + swz128(w*16 + lr, ks*64 + lg*16));
            acc2 = __builtin_amdgcn_mfma_f32_16x16x32_f16(fa, fb, acc2, 0, 0, 0);
        }
        if (p < 7) {
            char* Vn = KV[(p+1) & 1];
            *(f16x8*)(Vn + tid*16)        = v0;
            *(f16x8*)(Vn + 4096 + tid*16) = v1;
            __syncthreads();
        }
    }

    // ---- pass B: coalesced normalized attn write ----
#pragma unroll
    for (int jj = 0; jj < 8; ++jj) {
        const int idx = tid + jj*256;
        const int row = idx >> 7, c4 = idx & 127;
        const f16x4 pv = *(const f16x4*)(PS + swz1024(row, c4*8));
        const float it = invT_s[row];
        *(float4*)&attn[((size_t)z*SS + q0 + row)*SS + c4*4] =
            make_float4((float)pv[0]*it, (float)pv[1]*it, (float)pv[2]*it, (float)pv[3]*it);
    }

    // ---- w @ emb_v tail + epilogue ----
#pragma unroll
    for (int ks = 0; ks < 2; ++ks) {
        f16x8 fa;
        const float* wp = &QW[lr][ks*32 + lg*8];
#pragma unroll
        for (int j = 0; j < 8; ++j) fa[j] = (f16)wp[j];
        const f16x8 fb = *(const f16x8*)&evt[(size_t)(w*16 + lr)*RR + ks*32 + lg*8];
        acc2 = __builtin_amdgcn_mfma_f32_16x16x32_f16(fa, fb, acc2, 0, 0, 0);
    }
#pragma unroll
    for (int e = 0; e < 4; ++e)
        ctxh[((size_t)b*SS + q0 + lg*4 + e)*OO + h*DD + w*16 + lr] =
            (f16)(acc2[e] * invT_s[lg*4 + e]);
}

// ---------------------------------------------------------------------------
// out = ctx(2048x512 f16) @ Wo + bo, double-buffered f16 MFMA.
// ---------------------------------------------------------------------------
__global__ __launch_bounds__(256) void k_out(
    const f16* __restrict__ ctxh, const f16* __restrict__ WoT,
    const float* __restrict__ bo, float* __restrict__ out)
{
    const int n0 = blockIdx.x * 64;
    const int m0 = blockIdx.y * 64;
    __shared__ char Ab[2][8192];
    __shared__ char Bb[2][8192];
    const int tid = threadIdx.x;
    const int wid = tid >> 6, l = tid & 63;
    const int wr = wid >> 1, wc = wid & 1;
    const int lr = l & 15, lg = l >> 4;
    const int sr = tid >> 2, sc = (tid & 3) * 16;

    const f16* Ap = &ctxh[(size_t)(m0 + sr)*512 + sc];
    const f16* Bp = &WoT[(size_t)(n0 + sr)*512 + sc];

    f32x4 acc[2][2];
#pragma unroll
    for (int mi = 0; mi < 2; ++mi)
#pragma unroll
        for (int ni = 0; ni < 2; ++ni) acc[mi][ni] = (f32x4){0.f,0.f,0.f,0.f};

    f16x8 a0 = *(const f16x8*)Ap, a1 = *(const f16x8*)(Ap + 8);
    f16x8 b0 = *(const f16x8*)Bp, b1 = *(const f16x8*)(Bp + 8);
    *(f16x8*)(Ab[0] + swz128(sr, sc*2))    = a0;
    *(f16x8*)(Ab[0] + swz128(sr, sc*2+16)) = a1;
    *(f16x8*)(Bb[0] + swz128(sr, sc*2))    = b0;
    *(f16x8*)(Bb[0] + swz128(sr, sc*2+16)) = b1;
#pragma unroll
    for (int t = 0; t < 8; ++t) {
        __syncthreads();
        if (t < 7) {
            a0 = *(const f16x8*)(Ap + (t+1)*64); a1 = *(const f16x8*)(Ap + (t+1)*64 + 8);
            b0 = *(const f16x8*)(Bp + (t+1)*64); b1 = *(const f16x8*)(Bp + (t+1)*64 + 8);
        }
        const char* Ac = Ab[t & 1];
        const char* Bc = Bb[t & 1];
        f16x8 fa[2][2], fb[2][2];
#pragma unroll
        for (int mi = 0; mi < 2; ++mi) {
            const int row = wr*32 + mi*16 + lr;
#pragma unroll
            for (int ks = 0; ks < 2; ++ks)
                fa[mi][ks] = *(const f16x8*)(Ac + swz128(row, ks*64 + lg*16));
        }
#pragma unroll
        for (int ni = 0; ni < 2; ++ni) {
            const int row = wc*32 + ni*16 + lr;
#pragma unroll
            for (int ks = 0; ks < 2; ++ks)
                fb[ni][ks] = *(const f16x8*)(Bc + swz128(row, ks*64 + lg*16));
        }
#pragma unroll
        for (int ks = 0; ks < 2; ++ks)
#pragma unroll
            for (int mi = 0; mi < 2; ++mi)
#pragma unroll
                for (int ni = 0; ni < 2; ++ni)
                    acc[mi][ni] = __builtin_amdgcn_mfma_f32_16x16x32_f16(
                        fa[mi][ks], fb[ni][ks], acc[mi][ni], 0, 0, 0);
        if (t < 7) {
            char* An = Ab[(t+1) & 1];
            char* Bn = Bb[(t+1) & 1];
            *(f16x8*)(An + swz128(sr, sc*2))    = a0;
            *(f16x8*)(An + swz128(sr, sc*2+16)) = a1;
            *(f16x8*)(Bn + swz128(sr, sc*2))    = b0;
            *(f16x8*)(Bn + swz128(sr, sc*2+16)) = b1;
        }
    }

#pragma unroll
    for (int ni = 0; ni < 2; ++ni) {
        const int n = n0 + wc*32 + ni*16 + lr;
        const float bv_ = bo[n];
#pragma unroll
        for (int mi = 0; mi < 2; ++mi)
#pragma unroll
            for (int e = 0; e < 4; ++e) {
                const int m = m0 + wr*32 + mi*16 + lg*4 + e;
                out[(size_t)m*512 + n] = acc[mi][ni][e] + bv_;
            }
    }
}

extern "C" void kernel_launch(void* const* d_in, const int* in_sizes, int n_in,
                              void* d_out, int out_size, void* d_ws, size_t ws_size,
                              hipStream_t stream)
{
    const float* key   = (const float*)d_in[0];
    const float* value = (const float*)d_in[1];
    const float* query = (const float*)d_in[2];
    const void*  mask  = d_in[3];
    const int*   adj   = (const int*)d_in[4];
    const float* Wq    = (const float*)d_in[5];
    const float* bq    = (const float*)d_in[6];
    const float* Wk    = (const float*)d_in[7];
    const float* bk    = (const float*)d_in[8];
    const float* Wv    = (const float*)d_in[9];
    const float* bv    = (const float*)d_in[10];
    const float* Wo    = (const float*)d_in[11];
    const float* bo    = (const float*)d_in[12];
    const float* emb_k = (const float*)d_in[13];
    const float* emb_v = (const float*)d_in[14];

    char* w8 = (char*)d_ws;
    char* qhs = w8 + WS_QHS;
    char* khs = w8 + WS_KHS;
    char* vts = w8 + WS_VTS;
    f16*  ctxh = (f16*)(w8 + WS_CTXH);
    unsigned char* adj8p = (unsigned char*)(w8 + WS_ADJ8);
    f16*  WT  = (f16*)(w8 + WS_WT);
    f16*  WoT = WT + (size_t)3 * 262144;
    f16*  evt = (f16*)(w8 + WS_EVT);

    float* outp = (float*)d_out;                   // (B,S,OUT)
    float* attn = outp + (size_t)BB*SS*OO;         // (B,H,S,S)

    k_prep_all<<<1344, 256, 0, stream>>>(adj, mask, Wq, Wk, Wv, Wo, emb_v,
                                         adj8p, WT, evt);
    k_proj<<<dim3(8, 32, 3), 256, 0, stream>>>(query, key, value, WT,
                                               bq, bk, bv, qhs, khs, vts);
    k_attn<<<1024, 256, 0, stream>>>(qhs, khs, vts, adj8p, emb_k, evt, attn, ctxh);
    k_out <<<dim3(8, 32), 256, 0, stream>>>(ctxh, WoT, bo, outp);
}